// Round 6
// baseline (314.024 us; speedup 1.0000x reference)
//
#include <hip/hip_runtime.h>
#include <hip/hip_bf16.h>

#define N_NODES 8192
#define DEG     16
#define F_IN    1024
#define F_OUT   128
#define NH      8

typedef __bf16 bf16x8 __attribute__((ext_vector_type(8)));
typedef float  f32x4  __attribute__((ext_vector_type(4)));

__device__ __forceinline__ float bf2f(unsigned short u) {
    union { unsigned int i; float f; } v;
    v.i = ((unsigned int)u) << 16;
    return v.f;
}
__device__ __forceinline__ unsigned short f2bf(float f) {
    union { float f; unsigned int u; } v; v.f = f;
    unsigned int u = v.u + 0x7FFFu + ((v.u >> 16) & 1u);
    return (unsigned short)(u >> 16);
}
// Runtime dtype probe (validated: fp32 world). Wave-uniform.
__device__ __forceinline__ int detect_bf16(const unsigned int* __restrict__ w) {
    int hits = 0;
#pragma unroll
    for (int i = 0; i < 64; ++i) {
        unsigned int x = w[i * 131 + 17];
        int e = (x >> 7) & 0xFF;
        hits += (e >= 100 && e <= 140) ? 1 : 0;
    }
    return hits > 32;
}
__device__ __forceinline__ float rd_scalar(const void* p, int idx, int isbf) {
    return isbf ? bf2f(((const unsigned short*)p)[idx]) : ((const float*)p)[idx];
}
// async global->LDS, 16B per lane; LDS dest = wave-uniform base + lane*16
__device__ __forceinline__ void gload16(const void* g, void* l) {
    __builtin_amdgcn_global_load_lds(
        (const __attribute__((address_space(1))) void*)g,
        (__attribute__((address_space(3))) void*)l, 16, 0, 0);
}

// ===========================================================================
// DIAGNOSTIC ROUND: each kernel's (idempotent) body runs `reps` times so its
// dispatch exceeds the ~43 µs fills and enters the rocprof top-5.  reps is a
// runtime arg (opaque to the compiler -> no elision).  Output bit-identical.
// Host passes: prep x6, gemm x3, aggr x4.  Revert to reps=1 next round.
// ===========================================================================

// ---------------------------------------------------------------------------
// prep_inputs: blocks [0,4096): feat -> featb bf16; [4096,4352): W -> Wt
// ---------------------------------------------------------------------------
__global__ __launch_bounds__(256) void prep_inputs(
    const void* __restrict__ feat, const void* __restrict__ W,
    unsigned short* __restrict__ featb, unsigned short* __restrict__ Wt,
    int reps)
{
    const int isbf = detect_bf16((const unsigned int*)feat);
#pragma unroll 1
    for (int rep = 0; rep < reps; ++rep) {
        if (blockIdx.x < 4096) {
            size_t i8 = ((size_t)blockIdx.x * 256 + threadIdx.x) * 8;
            if (isbf) {
                *(uint4*)(featb + i8) = ((const uint4*)feat)[i8 / 8];
            } else {
                const float* s = (const float*)feat + i8;
                float4 u0 = *(const float4*)s;
                float4 u1 = *(const float4*)(s + 4);
                unsigned short t[8] = { f2bf(u0.x), f2bf(u0.y), f2bf(u0.z), f2bf(u0.w),
                                        f2bf(u1.x), f2bf(u1.y), f2bf(u1.z), f2bf(u1.w) };
                *(uint4*)(featb + i8) = *(const uint4*)t;
            }
        } else {
            __shared__ float tile[64][65];
            const int bx = blockIdx.x - 4096;
            const int h  = bx >> 5;
            const int kt = (bx >> 1) & 15;
            const int ot = bx & 1;
            const int t  = threadIdx.x;
#pragma unroll
            for (int i = 0; i < 16; ++i) {
                int id = i * 256 + t, r = id >> 6, c = id & 63;
                tile[r][c] = rd_scalar(W, ((h * 1024 + kt * 64 + r) * 128) + ot * 64 + c, isbf);
            }
            __syncthreads();
#pragma unroll
            for (int i = 0; i < 16; ++i) {
                int id = i * 256 + t, oc = id >> 6, kc = id & 63;
                Wt[(size_t)(h * 128 + ot * 64 + oc) * 1024 + kt * 64 + kc] = f2bf(tile[kc][oc]);
            }
            __syncthreads();   // rep separation: tile reused next rep
        }
    }
}

// ---------------------------------------------------------------------------
// gat_gemm3: h = feat @ W[h] + bW[h].  R5 structure (128x128 tile, BK=128 as
// two 64-k subtiles per barrier pair, 64 KB LDS, 2 blocks/CU, gload_lds +
// XOR swizzle, T1 bxp pin, fused score epilogue).  reps-wrapped.
// ---------------------------------------------------------------------------
__global__ __launch_bounds__(256) void gat_gemm3(
    const unsigned short* __restrict__ featb,  // [N, F_IN] bf16
    const unsigned short* __restrict__ Wt,     // [H, F_OUT, F_IN] bf16
    const void* __restrict__ raw_feat,
    const void* __restrict__ bW, const void* __restrict__ a,
    const void* __restrict__ ba,
    __hip_bfloat16* __restrict__ hbuf,
    float* __restrict__ sdst, float* __restrict__ ssrc,
    int reps)
{
    const int rawbf = detect_bf16((const unsigned int*)raw_feat);

    const int h   = blockIdx.y;
    const int bxp = ((blockIdx.x & 7) << 3) | (blockIdx.x >> 3);  // T1 XCD pin
    const int n0  = bxp * 128;
    const int tid = threadIdx.x;

    __shared__ __align__(16) unsigned short As[2][128 * 64];   // 32 KB
    __shared__ __align__(16) unsigned short Bs[2][128 * 64];   // 32 KB

    const int lane = tid & 63;
    const int wave = tid >> 6;
    const int quad = lane >> 4;
    const int l16  = lane & 15;
    const int sw   = l16 & 7;        // fragment-read swizzle key (= row&7)

    const unsigned short* wbase = Wt + (size_t)h * F_OUT * F_IN;

#pragma unroll 1
    for (int rep = 0; rep < reps; ++rep) {

        f32x4 acc[2][8];
#pragma unroll
        for (int i = 0; i < 2; ++i)
#pragma unroll
            for (int j = 0; j < 8; ++j) acc[i][j] = (f32x4)0.f;

        for (int k0 = 0; k0 < F_IN; k0 += 128) {
            // stage BOTH 64-k sub-tiles (A and B each 128x64) before one barrier
#pragma unroll
            for (int p = 0; p < 2; ++p) {
                const int kk0 = k0 + p * 64;
#pragma unroll
                for (int t = 0; t < 4; ++t) {
                    const int r0  = t * 32 + wave * 8;           // wave-uniform
                    const int row = r0 + (lane >> 3);
                    const int gc  = (lane & 7) ^ (row & 7);      // XOR swizzle
                    gload16(&featb[(size_t)(n0 + row) * F_IN + kk0 + gc * 8],
                            &As[p][r0 * 64]);
                    gload16(&wbase[(size_t)row * F_IN + kk0 + gc * 8],
                            &Bs[p][r0 * 64]);
                }
            }
            __syncthreads();   // one drain for 128 k of staging

#pragma unroll
            for (int p = 0; p < 2; ++p) {
#pragma unroll
                for (int ks = 0; ks < 2; ++ks) {
                    const int kc = ks * 4 + quad;
                    const int cs = (kc ^ sw) * 8;
                    bf16x8 af[2], bfr[8];
#pragma unroll
                    for (int rt = 0; rt < 2; ++rt)
                        af[rt] = *(const bf16x8*)&As[p][(wave * 32 + rt * 16 + l16) * 64 + cs];
#pragma unroll
                    for (int ct = 0; ct < 8; ++ct)
                        bfr[ct] = *(const bf16x8*)&Bs[p][(ct * 16 + l16) * 64 + cs];
#pragma unroll
                    for (int rt = 0; rt < 2; ++rt)
#pragma unroll
                        for (int ct = 0; ct < 8; ++ct)
                            acc[rt][ct] = __builtin_amdgcn_mfma_f32_16x16x32_bf16(
                                af[rt], bfr[ct], acc[rt][ct], 0, 0, 0);
                }
            }
            __syncthreads();
        }

        // h-tile store (D: col = lane&15, row = quad*4 + reg — m89/m91)
#pragma unroll
        for (int ct = 0; ct < 8; ++ct) {
            const int col = ct * 16 + l16;
            const float bwv = rd_scalar(bW, h * F_OUT + col, rawbf);
#pragma unroll
            for (int rt = 0; rt < 2; ++rt) {
                const int nrow = n0 + wave * 32 + rt * 16 + quad * 4;
                __hip_bfloat16* dst = hbuf + ((size_t)h * N_NODES + nrow) * F_OUT + col;
#pragma unroll
                for (int r = 0; r < 4; ++r)
                    dst[(size_t)r * F_OUT] = __float2bfloat16(acc[rt][ct][r] + bwv);
            }
        }

        // fused scores: reduce row dot a_dst/a_src over l16
        float adst[8], asrc[8];
#pragma unroll
        for (int ct = 0; ct < 8; ++ct) {
            const int col = ct * 16 + l16;
            adst[ct] = rd_scalar(a, h * 256 + col, rawbf);
            asrc[ct] = rd_scalar(a, h * 256 + 128 + col, rawbf);
        }
        float pd[2][4] = {}, ps[2][4] = {};
#pragma unroll
        for (int rt = 0; rt < 2; ++rt)
#pragma unroll
            for (int ct = 0; ct < 8; ++ct)
#pragma unroll
                for (int r = 0; r < 4; ++r) {
                    pd[rt][r] += acc[rt][ct][r] * adst[ct];
                    ps[rt][r] += acc[rt][ct][r] * asrc[ct];
                }
#pragma unroll
        for (int off = 1; off < 16; off <<= 1)
#pragma unroll
            for (int rt = 0; rt < 2; ++rt)
#pragma unroll
                for (int r = 0; r < 4; ++r) {
                    pd[rt][r] += __shfl_xor(pd[rt][r], off, 64);
                    ps[rt][r] += __shfl_xor(ps[rt][r], off, 64);
                }
        if (l16 == 0) {
            const float bav = rd_scalar(ba, h, rawbf);
#pragma unroll
            for (int rt = 0; rt < 2; ++rt) {
                const int base = n0 + wave * 32 + rt * 16 + quad * 4;
                float4 vd = { pd[rt][0] + bav, pd[rt][1] + bav,
                              pd[rt][2] + bav, pd[rt][3] + bav };
                float4 vs = { ps[rt][0], ps[rt][1], ps[rt][2], ps[rt][3] };
                *(float4*)&sdst[h * N_NODES + base] = vd;
                *(float4*)&ssrc[h * N_NODES + base] = vs;
            }
        }
    }
}

// ---------------------------------------------------------------------------
// gat_aggr4: XCD-pinned heads; high-TLP latency-bound gather.  reps-wrapped.
// ---------------------------------------------------------------------------
__global__ __launch_bounds__(256) void gat_aggr4(
    const unsigned short* __restrict__ hbuf,   // [H, N, F_OUT] bf16
    const int* __restrict__ adj,
    const float* __restrict__ sdst, const float* __restrict__ ssrc,
    const void* __restrict__ raw_feat, void* __restrict__ out,
    int reps)
{
    const int isbf = detect_bf16((const unsigned int*)raw_feat);
    const int h    = blockIdx.x;               // head == XCD slot
    const int wave = threadIdx.x >> 6;
    const int lane = threadIdx.x & 63;
    const int half = lane >> 5;
    const int l32  = lane & 31;
    const int n    = blockIdx.y * 8 + wave * 2 + half;

#pragma unroll 1
    for (int rep = 0; rep < reps; ++rep) {
        int nbr = n;                               // self edge is slot 16
        if (l32 < DEG) nbr = adj[n * DEG + l32];

        float s = -1e30f;
        if (l32 < 17) {
            float sv = sdst[h * N_NODES + n] + ssrc[h * N_NODES + nbr];
            s = sv > 0.f ? sv : 0.2f * sv;         // leaky_relu(0.2)
        }
        float m = s;
#pragma unroll
        for (int off = 1; off < 32; off <<= 1)     // xor stays within 32-half
            m = fmaxf(m, __shfl_xor(m, off, 64));
        float ev = (l32 < 17) ? __expf(s - m) : 0.f;
        float sum = ev;
#pragma unroll
        for (int off = 1; off < 32; off <<= 1)
            sum += __shfl_xor(sum, off, 64);
        ev *= (1.f / sum);                         // normalized alpha (lanes d<17)

        const unsigned short* hb = hbuf + (size_t)h * N_NODES * F_OUT;
        const int fc    = l32 * 4;
        const int sbase = half << 5;
        float a0 = 0.f, a1 = 0.f, a2 = 0.f, a3 = 0.f;
#pragma unroll
        for (int d = 0; d < 17; ++d) {
            const int   nb = __shfl(nbr, sbase + d, 64);
            const float av = __shfl(ev,  sbase + d, 64);
            uint2 pk = *(const uint2*)&hb[(size_t)nb * F_OUT + fc];
            a0 += av * bf2f((unsigned short)(pk.x & 0xffffu));
            a1 += av * bf2f((unsigned short)(pk.x >> 16));
            a2 += av * bf2f((unsigned short)(pk.y & 0xffffu));
            a3 += av * bf2f((unsigned short)(pk.y >> 16));
        }

        const size_t oidx = (size_t)n * (NH * F_OUT) + h * F_OUT + fc;
        if (isbf) {
            uint2 res;
            res.x = (unsigned int)f2bf(a0) | ((unsigned int)f2bf(a1) << 16);
            res.y = (unsigned int)f2bf(a2) | ((unsigned int)f2bf(a3) << 16);
            *(uint2*)&((unsigned short*)out)[oidx] = res;
        } else {
            float4 res = { a0, a1, a2, a3 };
            *(float4*)&((float*)out)[oidx] = res;
        }
    }
}

// ---------------------------------------------------------------------------
// Fallback tier — only if ws < 34.5 MiB.  UNCHANGED.
// ---------------------------------------------------------------------------
__global__ __launch_bounds__(256) void gat_gemm_fb(
    const void* __restrict__ feat, const void* __restrict__ W,
    const void* __restrict__ bW, __hip_bfloat16* __restrict__ hbuf)
{
    const int isbf = detect_bf16((const unsigned int*)feat);
    const int h = blockIdx.y, n0 = blockIdx.x * 128, tid = threadIdx.x;
    __shared__ __align__(16) unsigned short As[128][72];
    __shared__ __align__(16) unsigned short Bs[128][72];
    const int lane = tid & 63, wave = tid >> 6, quad = lane >> 4, l16 = lane & 15;
    f32x4 acc[2][8];
#pragma unroll
    for (int i = 0; i < 2; ++i)
#pragma unroll
        for (int j = 0; j < 8; ++j) acc[i][j] = (f32x4)0.f;
    for (int k0 = 0; k0 < F_IN; k0 += 64) {
        if (isbf) {
            const unsigned short* fbase = (const unsigned short*)feat + (size_t)n0 * F_IN;
            const unsigned short* wsrc  = (const unsigned short*)W +
                                          (size_t)h * F_IN * F_OUT + (size_t)k0 * F_OUT;
#pragma unroll
            for (int t = 0; t < 4; ++t) {
                int c = t * 256 + tid, row = c >> 3, kc = c & 7;
                *(uint4*)&As[row][kc * 8] = *(const uint4*)&fbase[row * F_IN + k0 + kc * 8];
            }
#pragma unroll
            for (int t = 0; t < 2; ++t) {
                int c = t * 256 + tid, kr2 = c >> 4, mm = c & 15, oc = mm * 8;
                uint4 w0 = *(const uint4*)&wsrc[(2 * kr2) * F_OUT + oc];
                uint4 w1 = *(const uint4*)&wsrc[(2 * kr2 + 1) * F_OUT + oc];
                const unsigned short* p0 = (const unsigned short*)&w0;
                const unsigned short* p1 = (const unsigned short*)&w1;
#pragma unroll
                for (int j = 0; j < 8; ++j) {
                    int i = (j + mm) & 7;
                    *(unsigned int*)&Bs[oc + i][2 * kr2] =
                        (unsigned int)p0[i] | ((unsigned int)p1[i] << 16);
                }
            }
        } else {
            const float* fbase = (const float*)feat + (size_t)n0 * F_IN;
            const float* wsrc  = (const float*)W +
                                 (size_t)h * F_IN * F_OUT + (size_t)k0 * F_OUT;
#pragma unroll
            for (int t = 0; t < 4; ++t) {
                int c = t * 256 + tid, row = c >> 3, kc = c & 7;
                const float* src = &fbase[row * F_IN + k0 + kc * 8];
                float4 u0 = *(const float4*)src, u1 = *(const float4*)(src + 4);
                unsigned short sh[8] = { f2bf(u0.x), f2bf(u0.y), f2bf(u0.z), f2bf(u0.w),
                                         f2bf(u1.x), f2bf(u1.y), f2bf(u1.z), f2bf(u1.w) };
                *(uint4*)&As[row][kc * 8] = *(const uint4*)sh;
            }
#pragma unroll
            for (int t = 0; t < 2; ++t) {
                int c = t * 256 + tid, kr2 = c >> 4, mm = c & 15, oc = mm * 8;
                const float* r0 = &wsrc[(2 * kr2) * F_OUT + oc];
                const float* r1 = &wsrc[(2 * kr2 + 1) * F_OUT + oc];
                float4 e0 = *(const float4*)r0, e1 = *(const float4*)(r0 + 4);
                float4 o0 = *(const float4*)r1, o1 = *(const float4*)(r1 + 4);
                unsigned short p0[8] = { f2bf(e0.x), f2bf(e0.y), f2bf(e0.z), f2bf(e0.w),
                                         f2bf(e1.x), f2bf(e1.y), f2bf(e1.z), f2bf(e1.w) };
                unsigned short p1[8] = { f2bf(o0.x), f2bf(o0.y), f2bf(o0.z), f2bf(o0.w),
                                         f2bf(o1.x), f2bf(o1.y), f2bf(o1.z), f2bf(o1.w) };
#pragma unroll
                for (int j = 0; j < 8; ++j) {
                    int i = (j + mm) & 7;
                    *(unsigned int*)&Bs[oc + i][2 * kr2] =
                        (unsigned int)p0[i] | ((unsigned int)p1[i] << 16);
                }
            }
        }
        __syncthreads();
#pragma unroll
        for (int ks = 0; ks < 2; ++ks) {
            const int kk = ks * 32 + quad * 8;
            bf16x8 af[2], bfr[8];
#pragma unroll
            for (int rt = 0; rt < 2; ++rt)
                af[rt] = *(const bf16x8*)&As[wave * 32 + rt * 16 + l16][kk];
#pragma unroll
            for (int ct = 0; ct < 8; ++ct)
                bfr[ct] = *(const bf16x8*)&Bs[ct * 16 + l16][kk];
#pragma unroll
            for (int rt = 0; rt < 2; ++rt)
#pragma unroll
                for (int ct = 0; ct < 8; ++ct)
                    acc[rt][ct] = __builtin_amdgcn_mfma_f32_16x16x32_bf16(
                        af[rt], bfr[ct], acc[rt][ct], 0, 0, 0);
        }
        __syncthreads();
    }
#pragma unroll
    for (int ct = 0; ct < 8; ++ct) {
        const int col = ct * 16 + l16;
        const float bwv = rd_scalar(bW, h * F_OUT + col, isbf);
#pragma unroll
        for (int rt = 0; rt < 2; ++rt) {
            const int nrow = n0 + wave * 32 + rt * 16 + quad * 4;
            __hip_bfloat16* dst = hbuf + ((size_t)h * N_NODES + nrow) * F_OUT + col;
#pragma unroll
            for (int r = 0; r < 4; ++r)
                dst[(size_t)r * F_OUT] = __float2bfloat16(acc[rt][ct][r] + bwv);
        }
    }
}

__global__ __launch_bounds__(256) void gat_aggr_fb(
    const __hip_bfloat16* __restrict__ hbuf, const int* __restrict__ adj,
    const void* __restrict__ a, const void* __restrict__ ba,
    void* __restrict__ out, const void* __restrict__ feat)
{
    const int isbf = detect_bf16((const unsigned int*)feat);
    const int n = blockIdx.x, wave = threadIdx.x >> 6, lane = threadIdx.x & 63;
    const int hh = blockIdx.y * 4 + wave;
    int nbr_reg = n;
    if (lane < DEG) nbr_reg = adj[n * DEG + lane];
    const int f0 = lane * 2;
    const float adst0 = rd_scalar(a, hh * 256 + f0, isbf);
    const float adst1 = rd_scalar(a, hh * 256 + f0 + 1, isbf);
    const float asrc0 = rd_scalar(a, hh * 256 + 128 + f0, isbf);
    const float asrc1 = rd_scalar(a, hh * 256 + 128 + f0 + 1, isbf);
    const float bav   = rd_scalar(ba, hh, isbf);
    const __hip_bfloat16* hb = hbuf + (size_t)hh * N_NODES * F_OUT;
    float v0[17], v1[17], red[18];
#pragma unroll
    for (int d = 0; d < 17; ++d) {
        int nb = __shfl(nbr_reg, d, 64);
        unsigned int pk = *(const unsigned int*)&hb[(size_t)nb * F_OUT + f0];
        v0[d] = bf2f((unsigned short)(pk & 0xffffu));
        v1[d] = bf2f((unsigned short)(pk >> 16));
        red[d] = v0[d] * asrc0 + v1[d] * asrc1;
    }
    red[17] = v0[16] * adst0 + v1[16] * adst1;
#pragma unroll
    for (int off = 1; off < 64; off <<= 1)
#pragma unroll
        for (int r = 0; r < 18; ++r) red[r] += __shfl_xor(red[r], off, 64);
    const float sd = red[17] + bav;
    float sc[17], mx = -1e30f;
#pragma unroll
    for (int d = 0; d < 17; ++d) {
        float s = sd + red[d];
        s = s > 0.f ? s : 0.2f * s;
        sc[d] = s; mx = fmaxf(mx, s);
    }
    float ssum = 0.f;
#pragma unroll
    for (int d = 0; d < 17; ++d) { sc[d] = __expf(sc[d] - mx); ssum += sc[d]; }
    const float inv = 1.f / ssum;
    float o0 = 0.f, o1 = 0.f;
#pragma unroll
    for (int d = 0; d < 17; ++d) { o0 += sc[d] * v0[d]; o1 += sc[d] * v1[d]; }
    o0 *= inv; o1 *= inv;
    const size_t oidx = (size_t)n * (NH * F_OUT) + hh * F_OUT + f0;
    if (isbf) {
        *(unsigned int*)&((unsigned short*)out)[oidx] =
            (unsigned int)f2bf(o0) | ((unsigned int)f2bf(o1) << 16);
    } else {
        float2 res; res.x = o0; res.y = o1;
        *(float2*)&((float*)out)[oidx] = res;
    }
}

// ---------------------------------------------------------------------------
// ws (256 MiB): hbuf 16M | sdst 256K | ssrc 256K | featb 16M | Wt 2M
// ---------------------------------------------------------------------------
extern "C" void kernel_launch(void* const* d_in, const int* in_sizes, int n_in,
                              void* d_out, int out_size, void* d_ws, size_t ws_size,
                              hipStream_t stream)
{
    const void* feat = d_in[0];
    const int*  adj  = (const int*)d_in[1];
    const void* W    = d_in[2];
    const void* bW   = d_in[3];
    const void* a    = d_in[4];
    const void* ba   = d_in[5];

    char* ws = (char*)d_ws;
    __hip_bfloat16* hbuf = (__hip_bfloat16*)ws;
    const size_t HB = (size_t)NH * N_NODES * F_OUT * 2;       // 16 MiB
    const size_t SC = (size_t)NH * N_NODES * 4;               // 256 KiB
    float* sdst = (float*)(ws + HB);
    float* ssrc = (float*)(ws + HB + SC);
    unsigned short* featb = (unsigned short*)(ws + HB + 2 * SC);
    unsigned short* Wt    = featb + (size_t)N_NODES * F_IN;
    const size_t needA = HB + 2 * SC +
        ((size_t)N_NODES * F_IN + (size_t)NH * F_IN * F_OUT) * 2; // 34.5 MiB

    if (ws_size >= needA) {
        // DIAGNOSTIC multipliers (divide top-5 dur_us by these next round):
        prep_inputs<<<4352, 256, 0, stream>>>(feat, W, featb, Wt, 6);
        gat_gemm3<<<dim3(64, 8), 256, 0, stream>>>(featb, Wt, feat, bW, a, ba,
                                                   hbuf, sdst, ssrc, 3);
        gat_aggr4<<<dim3(8, 1024), 256, 0, stream>>>((const unsigned short*)hbuf,
                                                     adj, sdst, ssrc, feat, d_out, 4);
    } else {
        gat_gemm_fb<<<dim3(64, 8), 256, 0, stream>>>(feat, W, bW, hbuf);
        gat_aggr_fb<<<dim3(8192, 2), 256, 0, stream>>>(hbuf, adj, a, ba, d_out, feat);
    }
}

// Round 7
// 150.882 us; speedup vs baseline: 2.0813x; 2.0813x over previous
//
#include <hip/hip_runtime.h>
#include <hip/hip_bf16.h>

#define N_NODES 8192
#define DEG     16
#define F_IN    1024
#define F_OUT   128
#define NH      8

typedef __bf16 bf16x8 __attribute__((ext_vector_type(8)));
typedef float  f32x4  __attribute__((ext_vector_type(4)));

__device__ __forceinline__ float bf2f(unsigned short u) {
    union { unsigned int i; float f; } v;
    v.i = ((unsigned int)u) << 16;
    return v.f;
}
__device__ __forceinline__ unsigned short f2bf(float f) {
    union { float f; unsigned int u; } v; v.f = f;
    unsigned int u = v.u + 0x7FFFu + ((v.u >> 16) & 1u);
    return (unsigned short)(u >> 16);
}
// Runtime dtype probe (validated: fp32 world). Wave-uniform.
__device__ __forceinline__ int detect_bf16(const unsigned int* __restrict__ w) {
    int hits = 0;
#pragma unroll
    for (int i = 0; i < 64; ++i) {
        unsigned int x = w[i * 131 + 17];
        int e = (x >> 7) & 0xFF;
        hits += (e >= 100 && e <= 140) ? 1 : 0;
    }
    return hits > 32;
}
__device__ __forceinline__ float rd_scalar(const void* p, int idx, int isbf) {
    return isbf ? bf2f(((const unsigned short*)p)[idx]) : ((const float*)p)[idx];
}
// async global->LDS, 16B per lane; LDS dest = wave-uniform base + lane*16
__device__ __forceinline__ void gload16(const void* g, void* l) {
    __builtin_amdgcn_global_load_lds(
        (const __attribute__((address_space(1))) void*)g,
        (__attribute__((address_space(3))) void*)l, 16, 0, 0);
}

// ---------------------------------------------------------------------------
// prep_inputs: blocks [0,4096): feat -> featb bf16; [4096,4352): W -> Wt
// (transpose via 64x64 LDS tile).  UNCHANGED (R5, reps removed).  ~9 us.
// ---------------------------------------------------------------------------
__global__ __launch_bounds__(256) void prep_inputs(
    const void* __restrict__ feat, const void* __restrict__ W,
    unsigned short* __restrict__ featb, unsigned short* __restrict__ Wt)
{
    const int isbf = detect_bf16((const unsigned int*)feat);
    if (blockIdx.x < 4096) {
        size_t i8 = ((size_t)blockIdx.x * 256 + threadIdx.x) * 8;
        if (isbf) {
            *(uint4*)(featb + i8) = ((const uint4*)feat)[i8 / 8];
        } else {
            const float* s = (const float*)feat + i8;
            float4 u0 = *(const float4*)s;
            float4 u1 = *(const float4*)(s + 4);
            unsigned short t[8] = { f2bf(u0.x), f2bf(u0.y), f2bf(u0.z), f2bf(u0.w),
                                    f2bf(u1.x), f2bf(u1.y), f2bf(u1.z), f2bf(u1.w) };
            *(uint4*)(featb + i8) = *(const uint4*)t;
        }
    } else {
        __shared__ float tile[64][65];
        const int bx = blockIdx.x - 4096;
        const int h  = bx >> 5;
        const int kt = (bx >> 1) & 15;
        const int ot = bx & 1;
        const int t  = threadIdx.x;
#pragma unroll
        for (int i = 0; i < 16; ++i) {
            int id = i * 256 + t, r = id >> 6, c = id & 63;
            tile[r][c] = rd_scalar(W, ((h * 1024 + kt * 64 + r) * 128) + ot * 64 + c, isbf);
        }
        __syncthreads();
#pragma unroll
        for (int i = 0; i < 16; ++i) {
            int id = i * 256 + t, oc = id >> 6, kc = id & 63;
            Wt[(size_t)(h * 128 + ot * 64 + oc) * 1024 + kt * 64 + kc] = f2bf(tile[kc][oc]);
        }
    }
}

// ---------------------------------------------------------------------------
// gat_gemm5: h = feat @ W[h] + bW[h].  R6 diagnostic: gemm = 41.5 us,
// MfmaUtil 17%, HBM 8% -> latency/barrier-drain-bound (the m97-family stall).
// THIS ROUND (T4, the one proven lever not yet correctly tried): counted
// vmcnt pipeline.  BK=64 double-buffer; prologue stages tiles 0,1 (16 loads
// in flight/wave); iteration t waits vmcnt(8) -- tile t's 8 loads complete,
// tile t+1's 8 REMAIN IN FLIGHT across both raw s_barriers (R2 failed
// because __syncthreads drains vmcnt to 0, killing exactly this overlap;
// m218: counted-vs-drain0 = +38..+73%).  After the compute barrier, tile
// t+2 is staged into the just-freed buffer.  vmcnt(0) only at t=15.
// setprio(1) around MFMA cluster (T5).  Same k accumulation order as R0/R5
// -> bit-identical output.  128x128 tile, 64 KB LDS, 2 blocks/CU, XOR
// swizzle, T1 bxp pin, fused score epilogue all carried over.
// ---------------------------------------------------------------------------
__global__ __launch_bounds__(256) void gat_gemm5(
    const unsigned short* __restrict__ featb,  // [N, F_IN] bf16
    const unsigned short* __restrict__ Wt,     // [H, F_OUT, F_IN] bf16
    const void* __restrict__ raw_feat,
    const void* __restrict__ bW, const void* __restrict__ a,
    const void* __restrict__ ba,
    __hip_bfloat16* __restrict__ hbuf,
    float* __restrict__ sdst, float* __restrict__ ssrc)
{
    const int rawbf = detect_bf16((const unsigned int*)raw_feat);

    const int h   = blockIdx.y;
    const int bxp = ((blockIdx.x & 7) << 3) | (blockIdx.x >> 3);  // T1 XCD pin
    const int n0  = bxp * 128;
    const int tid = threadIdx.x;

    __shared__ __align__(16) unsigned short As[2][128 * 64];   // 32 KB
    __shared__ __align__(16) unsigned short Bs[2][128 * 64];   // 32 KB

    const int lane = tid & 63;
    const int wave = tid >> 6;
    const int quad = lane >> 4;
    const int l16  = lane & 15;
    const int sw   = l16 & 7;        // fragment-read swizzle key (= row&7)
    const int srow   = lane >> 3;    // staging: row within 8-row strip
    const int schunk = lane & 7;     // staging: 8-short chunk

    f32x4 acc[2][8];
#pragma unroll
    for (int i = 0; i < 2; ++i)
#pragma unroll
        for (int j = 0; j < 8; ++j) acc[i][j] = (f32x4)0.f;

    const unsigned short* wbase = Wt + (size_t)h * F_OUT * F_IN;

    // stage one 64-k tile (A and B, 128 rows each) into slot s:
    // 8 gload16 issues per wave (4 strips x {A,B}).
    auto stage = [&](int kt, int s) {
        const int kk0 = kt * 64;
#pragma unroll
        for (int t = 0; t < 4; ++t) {
            const int r0  = t * 32 + wave * 8;           // wave-uniform
            const int row = r0 + srow;
            const int gc  = schunk ^ (row & 7);          // XOR swizzle
            gload16(&featb[(size_t)(n0 + row) * F_IN + kk0 + gc * 8],
                    &As[s][r0 * 64]);
            gload16(&wbase[(size_t)row * F_IN + kk0 + gc * 8],
                    &Bs[s][r0 * 64]);
        }
    };

    stage(0, 0);                     // 8 outstanding
    stage(1, 1);                     // 16 outstanding

    for (int t = 0; t < 16; ++t) {
        // tile t's 8 loads complete; tile t+1's 8 stay in flight (T4)
        if (t < 15) asm volatile("s_waitcnt vmcnt(8)" ::: "memory");
        else        asm volatile("s_waitcnt vmcnt(0)" ::: "memory");
        asm volatile("s_barrier" ::: "memory");   // raw: no compiler drain

        const int cur = t & 1;
#pragma unroll
        for (int ks = 0; ks < 2; ++ks) {
            const int kc = ks * 4 + quad;
            const int cs = (kc ^ sw) * 8;
            bf16x8 af[2], bfr[8];
#pragma unroll
            for (int rt = 0; rt < 2; ++rt)
                af[rt] = *(const bf16x8*)&As[cur][(wave * 32 + rt * 16 + l16) * 64 + cs];
#pragma unroll
            for (int ct = 0; ct < 8; ++ct)
                bfr[ct] = *(const bf16x8*)&Bs[cur][(ct * 16 + l16) * 64 + cs];
            __builtin_amdgcn_s_setprio(1);
#pragma unroll
            for (int rt = 0; rt < 2; ++rt)
#pragma unroll
                for (int ct = 0; ct < 8; ++ct)
                    acc[rt][ct] = __builtin_amdgcn_mfma_f32_16x16x32_bf16(
                        af[rt], bfr[ct], acc[rt][ct], 0, 0, 0);
            __builtin_amdgcn_s_setprio(0);
        }

        asm volatile("s_barrier" ::: "memory");   // all waves done reading cur
        if (t < 14) stage(t + 2, cur);            // refill freed buffer
    }

    // h-tile store (D: col = lane&15, row = quad*4 + reg — m89/m91)
#pragma unroll
    for (int ct = 0; ct < 8; ++ct) {
        const int col = ct * 16 + l16;
        const float bwv = rd_scalar(bW, h * F_OUT + col, rawbf);
#pragma unroll
        for (int rt = 0; rt < 2; ++rt) {
            const int nrow = n0 + wave * 32 + rt * 16 + quad * 4;
            __hip_bfloat16* dst = hbuf + ((size_t)h * N_NODES + nrow) * F_OUT + col;
#pragma unroll
            for (int r = 0; r < 4; ++r)
                dst[(size_t)r * F_OUT] = __float2bfloat16(acc[rt][ct][r] + bwv);
        }
    }

    // fused scores: reduce row dot a_dst/a_src over l16
    float adst[8], asrc[8];
#pragma unroll
    for (int ct = 0; ct < 8; ++ct) {
        const int col = ct * 16 + l16;
        adst[ct] = rd_scalar(a, h * 256 + col, rawbf);
        asrc[ct] = rd_scalar(a, h * 256 + 128 + col, rawbf);
    }
    float pd[2][4] = {}, ps[2][4] = {};
#pragma unroll
    for (int rt = 0; rt < 2; ++rt)
#pragma unroll
        for (int ct = 0; ct < 8; ++ct)
#pragma unroll
            for (int r = 0; r < 4; ++r) {
                pd[rt][r] += acc[rt][ct][r] * adst[ct];
                ps[rt][r] += acc[rt][ct][r] * asrc[ct];
            }
#pragma unroll
    for (int off = 1; off < 16; off <<= 1)
#pragma unroll
        for (int rt = 0; rt < 2; ++rt)
#pragma unroll
            for (int r = 0; r < 4; ++r) {
                pd[rt][r] += __shfl_xor(pd[rt][r], off, 64);
                ps[rt][r] += __shfl_xor(ps[rt][r], off, 64);
            }
    if (l16 == 0) {
        const float bav = rd_scalar(ba, h, rawbf);
#pragma unroll
        for (int rt = 0; rt < 2; ++rt) {
            const int base = n0 + wave * 32 + rt * 16 + quad * 4;
            float4 vd = { pd[rt][0] + bav, pd[rt][1] + bav,
                          pd[rt][2] + bav, pd[rt][3] + bav };
            float4 vs = { ps[rt][0], ps[rt][1], ps[rt][2], ps[rt][3] };
            *(float4*)&sdst[h * N_NODES + base] = vd;
            *(float4*)&ssrc[h * N_NODES + base] = vs;
        }
    }
}

// ---------------------------------------------------------------------------
// gat_aggr4: XCD-pinned heads; high-TLP latency-bound gather (~11 us).
// UNCHANGED (R5, reps removed).
// ---------------------------------------------------------------------------
__global__ __launch_bounds__(256) void gat_aggr4(
    const unsigned short* __restrict__ hbuf,   // [H, N, F_OUT] bf16
    const int* __restrict__ adj,
    const float* __restrict__ sdst, const float* __restrict__ ssrc,
    const void* __restrict__ raw_feat, void* __restrict__ out)
{
    const int isbf = detect_bf16((const unsigned int*)raw_feat);
    const int h    = blockIdx.x;               // head == XCD slot
    const int wave = threadIdx.x >> 6;
    const int lane = threadIdx.x & 63;
    const int half = lane >> 5;
    const int l32  = lane & 31;
    const int n    = blockIdx.y * 8 + wave * 2 + half;

    int nbr = n;                               // self edge is slot 16
    if (l32 < DEG) nbr = adj[n * DEG + l32];

    float s = -1e30f;
    if (l32 < 17) {
        float sv = sdst[h * N_NODES + n] + ssrc[h * N_NODES + nbr];
        s = sv > 0.f ? sv : 0.2f * sv;         // leaky_relu(0.2)
    }
    float m = s;
#pragma unroll
    for (int off = 1; off < 32; off <<= 1)     // xor stays within 32-half
        m = fmaxf(m, __shfl_xor(m, off, 64));
    float ev = (l32 < 17) ? __expf(s - m) : 0.f;
    float sum = ev;
#pragma unroll
    for (int off = 1; off < 32; off <<= 1)
        sum += __shfl_xor(sum, off, 64);
    ev *= (1.f / sum);                         // normalized alpha (lanes d<17)

    const unsigned short* hb = hbuf + (size_t)h * N_NODES * F_OUT;
    const int fc    = l32 * 4;
    const int sbase = half << 5;
    float a0 = 0.f, a1 = 0.f, a2 = 0.f, a3 = 0.f;
#pragma unroll
    for (int d = 0; d < 17; ++d) {
        const int   nb = __shfl(nbr, sbase + d, 64);
        const float av = __shfl(ev,  sbase + d, 64);
        uint2 pk = *(const uint2*)&hb[(size_t)nb * F_OUT + fc];
        a0 += av * bf2f((unsigned short)(pk.x & 0xffffu));
        a1 += av * bf2f((unsigned short)(pk.x >> 16));
        a2 += av * bf2f((unsigned short)(pk.y & 0xffffu));
        a3 += av * bf2f((unsigned short)(pk.y >> 16));
    }

    const size_t oidx = (size_t)n * (NH * F_OUT) + h * F_OUT + fc;
    if (isbf) {
        uint2 res;
        res.x = (unsigned int)f2bf(a0) | ((unsigned int)f2bf(a1) << 16);
        res.y = (unsigned int)f2bf(a2) | ((unsigned int)f2bf(a3) << 16);
        *(uint2*)&((unsigned short*)out)[oidx] = res;
    } else {
        float4 res = { a0, a1, a2, a3 };
        *(float4*)&((float*)out)[oidx] = res;
    }
}

// ---------------------------------------------------------------------------
// Fallback tier — only if ws < 34.5 MiB.  UNCHANGED.
// ---------------------------------------------------------------------------
__global__ __launch_bounds__(256) void gat_gemm_fb(
    const void* __restrict__ feat, const void* __restrict__ W,
    const void* __restrict__ bW, __hip_bfloat16* __restrict__ hbuf)
{
    const int isbf = detect_bf16((const unsigned int*)feat);
    const int h = blockIdx.y, n0 = blockIdx.x * 128, tid = threadIdx.x;
    __shared__ __align__(16) unsigned short As[128][72];
    __shared__ __align__(16) unsigned short Bs[128][72];
    const int lane = tid & 63, wave = tid >> 6, quad = lane >> 4, l16 = lane & 15;
    f32x4 acc[2][8];
#pragma unroll
    for (int i = 0; i < 2; ++i)
#pragma unroll
        for (int j = 0; j < 8; ++j) acc[i][j] = (f32x4)0.f;
    for (int k0 = 0; k0 < F_IN; k0 += 64) {
        if (isbf) {
            const unsigned short* fbase = (const unsigned short*)feat + (size_t)n0 * F_IN;
            const unsigned short* wsrc  = (const unsigned short*)W +
                                          (size_t)h * F_IN * F_OUT + (size_t)k0 * F_OUT;
#pragma unroll
            for (int t = 0; t < 4; ++t) {
                int c = t * 256 + tid, row = c >> 3, kc = c & 7;
                *(uint4*)&As[row][kc * 8] = *(const uint4*)&fbase[row * F_IN + k0 + kc * 8];
            }
#pragma unroll
            for (int t = 0; t < 2; ++t) {
                int c = t * 256 + tid, kr2 = c >> 4, mm = c & 15, oc = mm * 8;
                uint4 w0 = *(const uint4*)&wsrc[(2 * kr2) * F_OUT + oc];
                uint4 w1 = *(const uint4*)&wsrc[(2 * kr2 + 1) * F_OUT + oc];
                const unsigned short* p0 = (const unsigned short*)&w0;
                const unsigned short* p1 = (const unsigned short*)&w1;
#pragma unroll
                for (int j = 0; j < 8; ++j) {
                    int i = (j + mm) & 7;
                    *(unsigned int*)&Bs[oc + i][2 * kr2] =
                        (unsigned int)p0[i] | ((unsigned int)p1[i] << 16);
                }
            }
        } else {
            const float* fbase = (const float*)feat + (size_t)n0 * F_IN;
            const float* wsrc  = (const float*)W +
                                 (size_t)h * F_IN * F_OUT + (size_t)k0 * F_OUT;
#pragma unroll
            for (int t = 0; t < 4; ++t) {
                int c = t * 256 + tid, row = c >> 3, kc = c & 7;
                const float* src = &fbase[row * F_IN + k0 + kc * 8];
                float4 u0 = *(const float4*)src, u1 = *(const float4*)(src + 4);
                unsigned short sh[8] = { f2bf(u0.x), f2bf(u0.y), f2bf(u0.z), f2bf(u0.w),
                                         f2bf(u1.x), f2bf(u1.y), f2bf(u1.z), f2bf(u1.w) };
                *(uint4*)&As[row][kc * 8] = *(const uint4*)sh;
            }
#pragma unroll
            for (int t = 0; t < 2; ++t) {
                int c = t * 256 + tid, kr2 = c >> 4, mm = c & 15, oc = mm * 8;
                const float* r0 = &wsrc[(2 * kr2) * F_OUT + oc];
                const float* r1 = &wsrc[(2 * kr2 + 1) * F_OUT + oc];
                float4 e0 = *(const float4*)r0, e1 = *(const float4*)(r0 + 4);
                float4 o0 = *(const float4*)r1, o1 = *(const float4*)(r1 + 4);
                unsigned short p0[8] = { f2bf(e0.x), f2bf(e0.y), f2bf(e0.z), f2bf(e0.w),
                                         f2bf(e1.x), f2bf(e1.y), f2bf(e1.z), f2bf(e1.w) };
                unsigned short p1[8] = { f2bf(o0.x), f2bf(o0.y), f2bf(o0.z), f2bf(o0.w),
                                         f2bf(o1.x), f2bf(o1.y), f2bf(o1.z), f2bf(o1.w) };
#pragma unroll
                for (int j = 0; j < 8; ++j) {
                    int i = (j + mm) & 7;
                    *(unsigned int*)&Bs[oc + i][2 * kr2] =
                        (unsigned int)p0[i] | ((unsigned int)p1[i] << 16);
                }
            }
        }
        __syncthreads();
#pragma unroll
        for (int ks = 0; ks < 2; ++ks) {
            const int kk = ks * 32 + quad * 8;
            bf16x8 af[2], bfr[8];
#pragma unroll
            for (int rt = 0; rt < 2; ++rt)
                af[rt] = *(const bf16x8*)&As[wave * 32 + rt * 16 + l16][kk];
#pragma unroll
            for (int ct = 0; ct < 8; ++ct)
                bfr[ct] = *(const bf16x8*)&Bs[ct * 16 + l16][kk];
#pragma unroll
            for (int rt = 0; rt < 2; ++rt)
#pragma unroll
                for (int ct = 0; ct < 8; ++ct)
                    acc[rt][ct] = __builtin_amdgcn_mfma_f32_16x16x32_bf16(
                        af[rt], bfr[ct], acc[rt][ct], 0, 0, 0);
        }
        __syncthreads();
    }
#pragma unroll
    for (int ct = 0; ct < 8; ++ct) {
        const int col = ct * 16 + l16;
        const float bwv = rd_scalar(bW, h * F_OUT + col, isbf);
#pragma unroll
        for (int rt = 0; rt < 2; ++rt) {
            const int nrow = n0 + wave * 32 + rt * 16 + quad * 4;
            __hip_bfloat16* dst = hbuf + ((size_t)h * N_NODES + nrow) * F_OUT + col;
#pragma unroll
            for (int r = 0; r < 4; ++r)
                dst[(size_t)r * F_OUT] = __float2bfloat16(acc[rt][ct][r] + bwv);
        }
    }
}

__global__ __launch_bounds__(256) void gat_aggr_fb(
    const __hip_bfloat16* __restrict__ hbuf, const int* __restrict__ adj,
    const void* __restrict__ a, const void* __restrict__ ba,
    void* __restrict__ out, const void* __restrict__ feat)
{
    const int isbf = detect_bf16((const unsigned int*)feat);
    const int n = blockIdx.x, wave = threadIdx.x >> 6, lane = threadIdx.x & 63;
    const int hh = blockIdx.y * 4 + wave;
    int nbr_reg = n;
    if (lane < DEG) nbr_reg = adj[n * DEG + lane];
    const int f0 = lane * 2;
    const float adst0 = rd_scalar(a, hh * 256 + f0, isbf);
    const float adst1 = rd_scalar(a, hh * 256 + f0 + 1, isbf);
    const float asrc0 = rd_scalar(a, hh * 256 + 128 + f0, isbf);
    const float asrc1 = rd_scalar(a, hh * 256 + 128 + f0 + 1, isbf);
    const float bav   = rd_scalar(ba, hh, isbf);
    const __hip_bfloat16* hb = hbuf + (size_t)hh * N_NODES * F_OUT;
    float v0[17], v1[17], red[18];
#pragma unroll
    for (int d = 0; d < 17; ++d) {
        int nb = __shfl(nbr_reg, d, 64);
        unsigned int pk = *(const unsigned int*)&hb[(size_t)nb * F_OUT + f0];
        v0[d] = bf2f((unsigned short)(pk & 0xffffu));
        v1[d] = bf2f((unsigned short)(pk >> 16));
        red[d] = v0[d] * asrc0 + v1[d] * asrc1;
    }
    red[17] = v0[16] * adst0 + v1[16] * adst1;
#pragma unroll
    for (int off = 1; off < 64; off <<= 1)
#pragma unroll
        for (int r = 0; r < 18; ++r) red[r] += __shfl_xor(red[r], off, 64);
    const float sd = red[17] + bav;
    float sc[17], mx = -1e30f;
#pragma unroll
    for (int d = 0; d < 17; ++d) {
        float s = sd + red[d];
        s = s > 0.f ? s : 0.2f * s;
        sc[d] = s; mx = fmaxf(mx, s);
    }
    float ssum = 0.f;
#pragma unroll
    for (int d = 0; d < 17; ++d) { sc[d] = __expf(sc[d] - mx); ssum += sc[d]; }
    const float inv = 1.f / ssum;
    float o0 = 0.f, o1 = 0.f;
#pragma unroll
    for (int d = 0; d < 17; ++d) { o0 += sc[d] * v0[d]; o1 += sc[d] * v1[d]; }
    o0 *= inv; o1 *= inv;
    const size_t oidx = (size_t)n * (NH * F_OUT) + hh * F_OUT + f0;
    if (isbf) {
        *(unsigned int*)&((unsigned short*)out)[oidx] =
            (unsigned int)f2bf(o0) | ((unsigned int)f2bf(o1) << 16);
    } else {
        float2 res; res.x = o0; res.y = o1;
        *(float2*)&((float*)out)[oidx] = res;
    }
}

// ---------------------------------------------------------------------------
// ws (256 MiB): hbuf 16M | sdst 256K | ssrc 256K | featb 16M | Wt 2M
// Wall model (R6 diag): ~89 us harness floor + prep 9 + gemm + aggr 11.
// ---------------------------------------------------------------------------
extern "C" void kernel_launch(void* const* d_in, const int* in_sizes, int n_in,
                              void* d_out, int out_size, void* d_ws, size_t ws_size,
                              hipStream_t stream)
{
    const void* feat = d_in[0];
    const int*  adj  = (const int*)d_in[1];
    const void* W    = d_in[2];
    const void* bW   = d_in[3];
    const void* a    = d_in[4];
    const void* ba   = d_in[5];

    char* ws = (char*)d_ws;
    __hip_bfloat16* hbuf = (__hip_bfloat16*)ws;
    const size_t HB = (size_t)NH * N_NODES * F_OUT * 2;       // 16 MiB
    const size_t SC = (size_t)NH * N_NODES * 4;               // 256 KiB
    float* sdst = (float*)(ws + HB);
    float* ssrc = (float*)(ws + HB + SC);
    unsigned short* featb = (unsigned short*)(ws + HB + 2 * SC);
    unsigned short* Wt    = featb + (size_t)N_NODES * F_IN;
    const size_t needA = HB + 2 * SC +
        ((size_t)N_NODES * F_IN + (size_t)NH * F_IN * F_OUT) * 2; // 34.5 MiB

    if (ws_size >= needA) {
        prep_inputs<<<4352, 256, 0, stream>>>(feat, W, featb, Wt);
        gat_gemm5<<<dim3(64, 8), 256, 0, stream>>>(featb, Wt, feat, bW, a, ba,
                                                   hbuf, sdst, ssrc);
        gat_aggr4<<<dim3(8, 1024), 256, 0, stream>>>((const unsigned short*)hbuf,
                                                     adj, sdst, ssrc, feat, d_out);
    } else {
        gat_gemm_fb<<<dim3(64, 8), 256, 0, stream>>>(feat, W, bW, hbuf);
        gat_aggr_fb<<<dim3(8192, 2), 256, 0, stream>>>(hbuf, adj, a, ba, d_out, feat);
    }
}

// Round 8
// 148.079 us; speedup vs baseline: 2.1207x; 1.0189x over previous
//
#include <hip/hip_runtime.h>
#include <hip/hip_bf16.h>

#define N_NODES 8192
#define DEG     16
#define F_IN    1024
#define F_OUT   128
#define NH      8

typedef __bf16 bf16x8 __attribute__((ext_vector_type(8)));
typedef float  f32x4  __attribute__((ext_vector_type(4)));

__device__ __forceinline__ float bf2f(unsigned short u) {
    union { unsigned int i; float f; } v;
    v.i = ((unsigned int)u) << 16;
    return v.f;
}
__device__ __forceinline__ unsigned short f2bf(float f) {
    union { float f; unsigned int u; } v; v.f = f;
    unsigned int u = v.u + 0x7FFFu + ((v.u >> 16) & 1u);
    return (unsigned short)(u >> 16);
}
// Runtime dtype probe (validated: fp32 world). Wave-uniform.
__device__ __forceinline__ int detect_bf16(const unsigned int* __restrict__ w) {
    int hits = 0;
#pragma unroll
    for (int i = 0; i < 64; ++i) {
        unsigned int x = w[i * 131 + 17];
        int e = (x >> 7) & 0xFF;
        hits += (e >= 100 && e <= 140) ? 1 : 0;
    }
    return hits > 32;
}
__device__ __forceinline__ float rd_scalar(const void* p, int idx, int isbf) {
    return isbf ? bf2f(((const unsigned short*)p)[idx]) : ((const float*)p)[idx];
}
// async global->LDS, 16B per lane; LDS dest = wave-uniform base + lane*16
__device__ __forceinline__ void gload16(const void* g, void* l) {
    __builtin_amdgcn_global_load_lds(
        (const __attribute__((address_space(1))) void*)g,
        (__attribute__((address_space(3))) void*)l, 16, 0, 0);
}

// ---------------------------------------------------------------------------
// prep_inputs: blocks [0,4096): feat -> featb bf16; [4096,4352): W -> Wt
// (transpose via 64x64 LDS tile).  UNCHANGED.  ~9 us (R6 diag).
// ---------------------------------------------------------------------------
__global__ __launch_bounds__(256) void prep_inputs(
    const void* __restrict__ feat, const void* __restrict__ W,
    unsigned short* __restrict__ featb, unsigned short* __restrict__ Wt)
{
    const int isbf = detect_bf16((const unsigned int*)feat);
    if (blockIdx.x < 4096) {
        size_t i8 = ((size_t)blockIdx.x * 256 + threadIdx.x) * 8;
        if (isbf) {
            *(uint4*)(featb + i8) = ((const uint4*)feat)[i8 / 8];
        } else {
            const float* s = (const float*)feat + i8;
            float4 u0 = *(const float4*)s;
            float4 u1 = *(const float4*)(s + 4);
            unsigned short t[8] = { f2bf(u0.x), f2bf(u0.y), f2bf(u0.z), f2bf(u0.w),
                                    f2bf(u1.x), f2bf(u1.y), f2bf(u1.z), f2bf(u1.w) };
            *(uint4*)(featb + i8) = *(const uint4*)t;
        }
    } else {
        __shared__ float tile[64][65];
        const int bx = blockIdx.x - 4096;
        const int h  = bx >> 5;
        const int kt = (bx >> 1) & 15;
        const int ot = bx & 1;
        const int t  = threadIdx.x;
#pragma unroll
        for (int i = 0; i < 16; ++i) {
            int id = i * 256 + t, r = id >> 6, c = id & 63;
            tile[r][c] = rd_scalar(W, ((h * 1024 + kt * 64 + r) * 128) + ot * 64 + c, isbf);
        }
        __syncthreads();
#pragma unroll
        for (int i = 0; i < 16; ++i) {
            int id = i * 256 + t, oc = id >> 6, kc = id & 63;
            Wt[(size_t)(h * 128 + ot * 64 + oc) * 1024 + kt * 64 + kc] = f2bf(tile[kc][oc]);
        }
    }
}

// ---------------------------------------------------------------------------
// gat_gemm6: h = feat @ W[h] + bW[h].
// R6 diag: gemm latency-bound at VGPR=196 -> HW-capped 2 waves/SIMD (8/CU).
// R7: counted-vmcnt null -> rescheduling starved waves doesn't help; add
// waves instead.  THIS ROUND: same proven R0 K-loop (BK=128 stage-all, one
// drain, __syncthreads) but 8 waves/block (512 thr), each wave owns 32x64
// (wr=wave>>1 row band, wc=wave&1 col band) -> acc[2][4]+bfr[4] cuts live
// VGPRs to ~100; __launch_bounds__(512,4) caps at 128 -> 4 waves/SIMD =
// 16 waves/CU (2 blocks x 8 waves; LDS 2x64KB=128<=160).  2x TLP in a
// latency-bound regime.  Same k order per output element -> hbuf
// bit-identical.  Scores: per-wc partials combined via LDS (As reused
// after final barrier; R1-validated pattern).  T1 bxp pin kept.
// ---------------------------------------------------------------------------
__global__ __launch_bounds__(512, 4) void gat_gemm6(
    const unsigned short* __restrict__ featb,  // [N, F_IN] bf16
    const unsigned short* __restrict__ Wt,     // [H, F_OUT, F_IN] bf16
    const void* __restrict__ raw_feat,
    const void* __restrict__ bW, const void* __restrict__ a,
    const void* __restrict__ ba,
    __hip_bfloat16* __restrict__ hbuf,
    float* __restrict__ sdst, float* __restrict__ ssrc)
{
    const int rawbf = detect_bf16((const unsigned int*)raw_feat);

    const int h   = blockIdx.y;
    const int bxp = ((blockIdx.x & 7) << 3) | (blockIdx.x >> 3);  // T1 XCD pin
    const int n0  = bxp * 128;
    const int tid = threadIdx.x;

    __shared__ __align__(16) unsigned short As[2][128 * 64];   // 32 KB
    __shared__ __align__(16) unsigned short Bs[2][128 * 64];   // 32 KB

    const int lane = tid & 63;
    const int wave = tid >> 6;       // 0..7
    const int wr   = wave >> 1;      // 0..3 : 32-row band
    const int wc   = wave & 1;       // 0..1 : 64-col band
    const int quad = lane >> 4;
    const int l16  = lane & 15;
    const int sw   = l16 & 7;        // fragment-read swizzle key (= row&7)
    const int srow   = lane >> 3;    // staging: row within 8-row strip
    const int schunk = lane & 7;     // staging: 8-short chunk

    f32x4 acc[2][4];
#pragma unroll
    for (int i = 0; i < 2; ++i)
#pragma unroll
        for (int j = 0; j < 4; ++j) acc[i][j] = (f32x4)0.f;

    const unsigned short* wbase = Wt + (size_t)h * F_OUT * F_IN;

    for (int k0 = 0; k0 < F_IN; k0 += 128) {
        // stage BOTH 64-k sub-tiles (A and B each 128x64) before one barrier.
        // 8 waves: 2 rounds of 64 rows each per matrix.
#pragma unroll
        for (int p = 0; p < 2; ++p) {
            const int kk0 = k0 + p * 64;
#pragma unroll
            for (int t = 0; t < 2; ++t) {
                const int r0  = t * 64 + wave * 8;           // wave-uniform
                const int row = r0 + srow;
                const int gc  = schunk ^ (row & 7);          // XOR swizzle
                gload16(&featb[(size_t)(n0 + row) * F_IN + kk0 + gc * 8],
                        &As[p][r0 * 64]);
                gload16(&wbase[(size_t)row * F_IN + kk0 + gc * 8],
                        &Bs[p][r0 * 64]);
            }
        }
        __syncthreads();   // one drain for 128 k of staging

#pragma unroll
        for (int p = 0; p < 2; ++p) {
#pragma unroll
            for (int ks = 0; ks < 2; ++ks) {
                const int kc = ks * 4 + quad;
                const int cs = (kc ^ sw) * 8;
                bf16x8 af[2], bfr[4];
#pragma unroll
                for (int rt = 0; rt < 2; ++rt)
                    af[rt] = *(const bf16x8*)&As[p][(wr * 32 + rt * 16 + l16) * 64 + cs];
#pragma unroll
                for (int ct = 0; ct < 4; ++ct)
                    bfr[ct] = *(const bf16x8*)&Bs[p][(wc * 64 + ct * 16 + l16) * 64 + cs];
#pragma unroll
                for (int rt = 0; rt < 2; ++rt)
#pragma unroll
                    for (int ct = 0; ct < 4; ++ct)
                        acc[rt][ct] = __builtin_amdgcn_mfma_f32_16x16x32_bf16(
                            af[rt], bfr[ct], acc[rt][ct], 0, 0, 0);
            }
        }
        __syncthreads();
    }

    // ---- h-tile store (D: col = lane&15, row = quad*4 + reg — m89/m91) ----
#pragma unroll
    for (int ct = 0; ct < 4; ++ct) {
        const int col = wc * 64 + ct * 16 + l16;
        const float bwv = rd_scalar(bW, h * F_OUT + col, rawbf);
#pragma unroll
        for (int rt = 0; rt < 2; ++rt) {
            const int nrow = n0 + wr * 32 + rt * 16 + quad * 4;
            __hip_bfloat16* dst = hbuf + ((size_t)h * N_NODES + nrow) * F_OUT + col;
#pragma unroll
            for (int r = 0; r < 4; ++r)
                dst[(size_t)r * F_OUT] = __float2bfloat16(acc[rt][ct][r] + bwv);
        }
    }

    // ---- fused scores: per-wc partial dot, then cross-wc LDS combine ----
    float adst[4], asrc[4];
#pragma unroll
    for (int ct = 0; ct < 4; ++ct) {
        const int col = wc * 64 + ct * 16 + l16;
        adst[ct] = rd_scalar(a, h * 256 + col, rawbf);
        asrc[ct] = rd_scalar(a, h * 256 + 128 + col, rawbf);
    }
    float pd[2][4] = {}, ps[2][4] = {};
#pragma unroll
    for (int rt = 0; rt < 2; ++rt)
#pragma unroll
        for (int ct = 0; ct < 4; ++ct)
#pragma unroll
            for (int r = 0; r < 4; ++r) {
                pd[rt][r] += acc[rt][ct][r] * adst[ct];
                ps[rt][r] += acc[rt][ct][r] * asrc[ct];
            }
#pragma unroll
    for (int off = 1; off < 16; off <<= 1)
#pragma unroll
        for (int rt = 0; rt < 2; ++rt)
#pragma unroll
            for (int r = 0; r < 4; ++r) {
                pd[rt][r] += __shfl_xor(pd[rt][r], off, 64);
                ps[rt][r] += __shfl_xor(ps[rt][r], off, 64);
            }

    // sred[wr][wc][dst/src][row32] reuses As (free after final barrier)
    float* sred = (float*)&As[0][0];
    if (l16 == 0) {
#pragma unroll
        for (int rt = 0; rt < 2; ++rt)
#pragma unroll
            for (int r = 0; r < 4; ++r) {
                const int row32 = rt * 16 + quad * 4 + r;
                sred[((wr * 2 + wc) * 2 + 0) * 32 + row32] = pd[rt][r];
                sred[((wr * 2 + wc) * 2 + 1) * 32 + row32] = ps[rt][r];
            }
    }
    __syncthreads();
    if (wc == 0 && lane < 32) {
        const float bav = rd_scalar(ba, h, rawbf);
        const float vd = sred[((wr * 2 + 0) * 2 + 0) * 32 + lane]
                       + sred[((wr * 2 + 1) * 2 + 0) * 32 + lane] + bav;
        const float vs = sred[((wr * 2 + 0) * 2 + 1) * 32 + lane]
                       + sred[((wr * 2 + 1) * 2 + 1) * 32 + lane];
        const int nrow = n0 + wr * 32 + lane;
        sdst[h * N_NODES + nrow] = vd;
        ssrc[h * N_NODES + nrow] = vs;
    }
}

// ---------------------------------------------------------------------------
// gat_aggr4: XCD-pinned heads; high-TLP latency-bound gather (~11 us).
// UNCHANGED.
// ---------------------------------------------------------------------------
__global__ __launch_bounds__(256) void gat_aggr4(
    const unsigned short* __restrict__ hbuf,   // [H, N, F_OUT] bf16
    const int* __restrict__ adj,
    const float* __restrict__ sdst, const float* __restrict__ ssrc,
    const void* __restrict__ raw_feat, void* __restrict__ out)
{
    const int isbf = detect_bf16((const unsigned int*)raw_feat);
    const int h    = blockIdx.x;               // head == XCD slot
    const int wave = threadIdx.x >> 6;
    const int lane = threadIdx.x & 63;
    const int half = lane >> 5;
    const int l32  = lane & 31;
    const int n    = blockIdx.y * 8 + wave * 2 + half;

    int nbr = n;                               // self edge is slot 16
    if (l32 < DEG) nbr = adj[n * DEG + l32];

    float s = -1e30f;
    if (l32 < 17) {
        float sv = sdst[h * N_NODES + n] + ssrc[h * N_NODES + nbr];
        s = sv > 0.f ? sv : 0.2f * sv;         // leaky_relu(0.2)
    }
    float m = s;
#pragma unroll
    for (int off = 1; off < 32; off <<= 1)     // xor stays within 32-half
        m = fmaxf(m, __shfl_xor(m, off, 64));
    float ev = (l32 < 17) ? __expf(s - m) : 0.f;
    float sum = ev;
#pragma unroll
    for (int off = 1; off < 32; off <<= 1)
        sum += __shfl_xor(sum, off, 64);
    ev *= (1.f / sum);                         // normalized alpha (lanes d<17)

    const unsigned short* hb = hbuf + (size_t)h * N_NODES * F_OUT;
    const int fc    = l32 * 4;
    const int sbase = half << 5;
    float a0 = 0.f, a1 = 0.f, a2 = 0.f, a3 = 0.f;
#pragma unroll
    for (int d = 0; d < 17; ++d) {
        const int   nb = __shfl(nbr, sbase + d, 64);
        const float av = __shfl(ev,  sbase + d, 64);
        uint2 pk = *(const uint2*)&hb[(size_t)nb * F_OUT + fc];
        a0 += av * bf2f((unsigned short)(pk.x & 0xffffu));
        a1 += av * bf2f((unsigned short)(pk.x >> 16));
        a2 += av * bf2f((unsigned short)(pk.y & 0xffffu));
        a3 += av * bf2f((unsigned short)(pk.y >> 16));
    }

    const size_t oidx = (size_t)n * (NH * F_OUT) + h * F_OUT + fc;
    if (isbf) {
        uint2 res;
        res.x = (unsigned int)f2bf(a0) | ((unsigned int)f2bf(a1) << 16);
        res.y = (unsigned int)f2bf(a2) | ((unsigned int)f2bf(a3) << 16);
        *(uint2*)&((unsigned short*)out)[oidx] = res;
    } else {
        float4 res = { a0, a1, a2, a3 };
        *(float4*)&((float*)out)[oidx] = res;
    }
}

// ---------------------------------------------------------------------------
// Fallback tier — only if ws < 34.5 MiB.  UNCHANGED.
// ---------------------------------------------------------------------------
__global__ __launch_bounds__(256) void gat_gemm_fb(
    const void* __restrict__ feat, const void* __restrict__ W,
    const void* __restrict__ bW, __hip_bfloat16* __restrict__ hbuf)
{
    const int isbf = detect_bf16((const unsigned int*)feat);
    const int h = blockIdx.y, n0 = blockIdx.x * 128, tid = threadIdx.x;
    __shared__ __align__(16) unsigned short As[128][72];
    __shared__ __align__(16) unsigned short Bs[128][72];
    const int lane = tid & 63, wave = tid >> 6, quad = lane >> 4, l16 = lane & 15;
    f32x4 acc[2][8];
#pragma unroll
    for (int i = 0; i < 2; ++i)
#pragma unroll
        for (int j = 0; j < 8; ++j) acc[i][j] = (f32x4)0.f;
    for (int k0 = 0; k0 < F_IN; k0 += 64) {
        if (isbf) {
            const unsigned short* fbase = (const unsigned short*)feat + (size_t)n0 * F_IN;
            const unsigned short* wsrc  = (const unsigned short*)W +
                                          (size_t)h * F_IN * F_OUT + (size_t)k0 * F_OUT;
#pragma unroll
            for (int t = 0; t < 4; ++t) {
                int c = t * 256 + tid, row = c >> 3, kc = c & 7;
                *(uint4*)&As[row][kc * 8] = *(const uint4*)&fbase[row * F_IN + k0 + kc * 8];
            }
#pragma unroll
            for (int t = 0; t < 2; ++t) {
                int c = t * 256 + tid, kr2 = c >> 4, mm = c & 15, oc = mm * 8;
                uint4 w0 = *(const uint4*)&wsrc[(2 * kr2) * F_OUT + oc];
                uint4 w1 = *(const uint4*)&wsrc[(2 * kr2 + 1) * F_OUT + oc];
                const unsigned short* p0 = (const unsigned short*)&w0;
                const unsigned short* p1 = (const unsigned short*)&w1;
#pragma unroll
                for (int j = 0; j < 8; ++j) {
                    int i = (j + mm) & 7;
                    *(unsigned int*)&Bs[oc + i][2 * kr2] =
                        (unsigned int)p0[i] | ((unsigned int)p1[i] << 16);
                }
            }
        } else {
            const float* fbase = (const float*)feat + (size_t)n0 * F_IN;
            const float* wsrc  = (const float*)W +
                                 (size_t)h * F_IN * F_OUT + (size_t)k0 * F_OUT;
#pragma unroll
            for (int t = 0; t < 4; ++t) {
                int c = t * 256 + tid, row = c >> 3, kc = c & 7;
                const float* src = &fbase[row * F_IN + k0 + kc * 8];
                float4 u0 = *(const float4*)src, u1 = *(const float4*)(src + 4);
                unsigned short sh[8] = { f2bf(u0.x), f2bf(u0.y), f2bf(u0.z), f2bf(u0.w),
                                         f2bf(u1.x), f2bf(u1.y), f2bf(u1.z), f2bf(u1.w) };
                *(uint4*)&As[row][kc * 8] = *(const uint4*)sh;
            }
#pragma unroll
            for (int t = 0; t < 2; ++t) {
                int c = t * 256 + tid, kr2 = c >> 4, mm = c & 15, oc = mm * 8;
                const float* r0 = &wsrc[(2 * kr2) * F_OUT + oc];
                const float* r1 = &wsrc[(2 * kr2 + 1) * F_OUT + oc];
                float4 e0 = *(const float4*)r0, e1 = *(const float4*)(r0 + 4);
                float4 o0 = *(const float4*)r1, o1 = *(const float4*)(r1 + 4);
                unsigned short p0[8] = { f2bf(e0.x), f2bf(e0.y), f2bf(e0.z), f2bf(e0.w),
                                         f2bf(e1.x), f2bf(e1.y), f2bf(e1.z), f2bf(e1.w) };
                unsigned short p1[8] = { f2bf(o0.x), f2bf(o0.y), f2bf(o0.z), f2bf(o0.w),
                                         f2bf(o1.x), f2bf(o1.y), f2bf(o1.z), f2bf(o1.w) };
#pragma unroll
                for (int j = 0; j < 8; ++j) {
                    int i = (j + mm) & 7;
                    *(unsigned int*)&Bs[oc + i][2 * kr2] =
                        (unsigned int)p0[i] | ((unsigned int)p1[i] << 16);
                }
            }
        }
        __syncthreads();
#pragma unroll
        for (int ks = 0; ks < 2; ++ks) {
            const int kk = ks * 32 + quad * 8;
            bf16x8 af[2], bfr[8];
#pragma unroll
            for (int rt = 0; rt < 2; ++rt)
                af[rt] = *(const bf16x8*)&As[wave * 32 + rt * 16 + l16][kk];
#pragma unroll
            for (int ct = 0; ct < 8; ++ct)
                bfr[ct] = *(const bf16x8*)&Bs[ct * 16 + l16][kk];
#pragma unroll
            for (int rt = 0; rt < 2; ++rt)
#pragma unroll
                for (int ct = 0; ct < 8; ++ct)
                    acc[rt][ct] = __builtin_amdgcn_mfma_f32_16x16x32_bf16(
                        af[rt], bfr[ct], acc[rt][ct], 0, 0, 0);
        }
        __syncthreads();
    }
#pragma unroll
    for (int ct = 0; ct < 8; ++ct) {
        const int col = ct * 16 + l16;
        const float bwv = rd_scalar(bW, h * F_OUT + col, isbf);
#pragma unroll
        for (int rt = 0; rt < 2; ++rt) {
            const int nrow = n0 + wave * 32 + rt * 16 + quad * 4;
            __hip_bfloat16* dst = hbuf + ((size_t)h * N_NODES + nrow) * F_OUT + col;
#pragma unroll
            for (int r = 0; r < 4; ++r)
                dst[(size_t)r * F_OUT] = __float2bfloat16(acc[rt][ct][r] + bwv);
        }
    }
}

__global__ __launch_bounds__(256) void gat_aggr_fb(
    const __hip_bfloat16* __restrict__ hbuf, const int* __restrict__ adj,
    const void* __restrict__ a, const void* __restrict__ ba,
    void* __restrict__ out, const void* __restrict__ feat)
{
    const int isbf = detect_bf16((const unsigned int*)feat);
    const int n = blockIdx.x, wave = threadIdx.x >> 6, lane = threadIdx.x & 63;
    const int hh = blockIdx.y * 4 + wave;
    int nbr_reg = n;
    if (lane < DEG) nbr_reg = adj[n * DEG + lane];
    const int f0 = lane * 2;
    const float adst0 = rd_scalar(a, hh * 256 + f0, isbf);
    const float adst1 = rd_scalar(a, hh * 256 + f0 + 1, isbf);
    const float asrc0 = rd_scalar(a, hh * 256 + 128 + f0, isbf);
    const float asrc1 = rd_scalar(a, hh * 256 + 128 + f0 + 1, isbf);
    const float bav   = rd_scalar(ba, hh, isbf);
    const __hip_bfloat16* hb = hbuf + (size_t)hh * N_NODES * F_OUT;
    float v0[17], v1[17], red[18];
#pragma unroll
    for (int d = 0; d < 17; ++d) {
        int nb = __shfl(nbr_reg, d, 64);
        unsigned int pk = *(const unsigned int*)&hb[(size_t)nb * F_OUT + f0];
        v0[d] = bf2f((unsigned short)(pk & 0xffffu));
        v1[d] = bf2f((unsigned short)(pk >> 16));
        red[d] = v0[d] * asrc0 + v1[d] * asrc1;
    }
    red[17] = v0[16] * adst0 + v1[16] * adst1;
#pragma unroll
    for (int off = 1; off < 64; off <<= 1)
#pragma unroll
        for (int r = 0; r < 18; ++r) red[r] += __shfl_xor(red[r], off, 64);
    const float sd = red[17] + bav;
    float sc[17], mx = -1e30f;
#pragma unroll
    for (int d = 0; d < 17; ++d) {
        float s = sd + red[d];
        s = s > 0.f ? s : 0.2f * s;
        sc[d] = s; mx = fmaxf(mx, s);
    }
    float ssum = 0.f;
#pragma unroll
    for (int d = 0; d < 17; ++d) { sc[d] = __expf(sc[d] - mx); ssum += sc[d]; }
    const float inv = 1.f / ssum;
    float o0 = 0.f, o1 = 0.f;
#pragma unroll
    for (int d = 0; d < 17; ++d) { o0 += sc[d] * v0[d]; o1 += sc[d] * v1[d]; }
    o0 *= inv; o1 *= inv;
    const size_t oidx = (size_t)n * (NH * F_OUT) + hh * F_OUT + f0;
    if (isbf) {
        *(unsigned int*)&((unsigned short*)out)[oidx] =
            (unsigned int)f2bf(o0) | ((unsigned int)f2bf(o1) << 16);
    } else {
        float2 res; res.x = o0; res.y = o1;
        *(float2*)&((float*)out)[oidx] = res;
    }
}

// ---------------------------------------------------------------------------
// ws (256 MiB): hbuf 16M | sdst 256K | ssrc 256K | featb 16M | Wt 2M
// Wall model (R6 diag): ~89 us harness floor + prep 9 + gemm + aggr 11.
// ---------------------------------------------------------------------------
extern "C" void kernel_launch(void* const* d_in, const int* in_sizes, int n_in,
                              void* d_out, int out_size, void* d_ws, size_t ws_size,
                              hipStream_t stream)
{
    const void* feat = d_in[0];
    const int*  adj  = (const int*)d_in[1];
    const void* W    = d_in[2];
    const void* bW   = d_in[3];
    const void* a    = d_in[4];
    const void* ba   = d_in[5];

    char* ws = (char*)d_ws;
    __hip_bfloat16* hbuf = (__hip_bfloat16*)ws;
    const size_t HB = (size_t)NH * N_NODES * F_OUT * 2;       // 16 MiB
    const size_t SC = (size_t)NH * N_NODES * 4;               // 256 KiB
    float* sdst = (float*)(ws + HB);
    float* ssrc = (float*)(ws + HB + SC);
    unsigned short* featb = (unsigned short*)(ws + HB + 2 * SC);
    unsigned short* Wt    = featb + (size_t)N_NODES * F_IN;
    const size_t needA = HB + 2 * SC +
        ((size_t)N_NODES * F_IN + (size_t)NH * F_IN * F_OUT) * 2; // 34.5 MiB

    if (ws_size >= needA) {
        prep_inputs<<<4352, 256, 0, stream>>>(feat, W, featb, Wt);
        gat_gemm6<<<dim3(64, 8), 512, 0, stream>>>(featb, Wt, feat, bW, a, ba,
                                                   hbuf, sdst, ssrc);
        gat_aggr4<<<dim3(8, 1024), 256, 0, stream>>>((const unsigned short*)hbuf,
                                                     adj, sdst, ssrc, feat, d_out);
    } else {
        gat_gemm_fb<<<dim3(64, 8), 256, 0, stream>>>(feat, W, bW, hbuf);
        gat_aggr_fb<<<dim3(8192, 2), 256, 0, stream>>>(hbuf, adj, a, ba, d_out, feat);
    }
}